// Round 1
// baseline (929.109 us; speedup 1.0000x reference)
//
#include <hip/hip_runtime.h>
#include <hip/hip_bf16.h>

typedef __bf16 bf16x8 __attribute__((ext_vector_type(8)));
typedef float  f32x4  __attribute__((ext_vector_type(4)));

#define DIM    512
#define DINNER 1024
#define SEQL   256
#define BATCH  2
#define NLAYER 7   // layer 7's mixer output is discarded by the reference

// ---------------- transpose in: res[b][l][d] = x[b][d][l] ----------------
__global__ __launch_bounds__(256) void k_transpose_in(const float* __restrict__ x,
                                                      float* __restrict__ res) {
  int idx = blockIdx.x * 256 + threadIdx.x;          // over B*L*DIM = 262144
  int d = idx & (DIM - 1);
  int l = (idx >> 9) & (SEQL - 1);
  int b = idx >> 17;
  res[idx] = x[((size_t)(b * DIM + d) << 8) + l];
}

// ---------------- transpose out: out[b][c][l] = res[b][l][c] ----------------
__global__ __launch_bounds__(256) void k_transpose_out(const float* __restrict__ res,
                                                       float* __restrict__ out) {
  int idx = blockIdx.x * 256 + threadIdx.x;          // over B*DIM*L
  int l = idx & (SEQL - 1);
  int c = (idx >> 8) & (DIM - 1);
  int b = idx >> 17;
  out[idx] = res[((size_t)(b * SEQL + l) << 9) + c];
}

// ---------------- f32 -> bf16 cast (4 per thread) ----------------
__global__ __launch_bounds__(256) void k_cast_bf16(const float* __restrict__ src,
                                                   __hip_bfloat16* __restrict__ dst, int n4) {
  int i = blockIdx.x * 256 + threadIdx.x;
  if (i >= n4) return;
  float4 v = reinterpret_cast<const float4*>(src)[i];
  struct alignas(8) B4 { __hip_bfloat16 a, b, c, d; };
  B4 o{ (__hip_bfloat16)v.x, (__hip_bfloat16)v.y, (__hip_bfloat16)v.z, (__hip_bfloat16)v.w };
  reinterpret_cast<B4*>(dst)[i] = o;
}

// ---------------- rmsnorm + bf16 cast: one wave per row ----------------
__global__ __launch_bounds__(256) void k_rmsnorm(const float* __restrict__ res,
                                                 const float* __restrict__ w,
                                                 __hip_bfloat16* __restrict__ hn) {
  int wid = threadIdx.x >> 6, lane = threadIdx.x & 63;
  int row = (blockIdx.x << 2) + wid;                 // 512 rows, 4 per block
  const float* r = res + ((size_t)row << 9);
  float v[8];
  float ss = 0.f;
#pragma unroll
  for (int j = 0; j < 8; ++j) { v[j] = r[lane + (j << 6)]; ss = fmaf(v[j], v[j], ss); }
#pragma unroll
  for (int m = 1; m < 64; m <<= 1) ss += __shfl_xor(ss, m);
  float inv = rsqrtf(ss * (1.0f / 512.0f) + 1e-5f);
  __hip_bfloat16* o = hn + ((size_t)row << 9);
#pragma unroll
  for (int j = 0; j < 8; ++j) o[lane + (j << 6)] = (__hip_bfloat16)(v[j] * inv * w[lane + (j << 6)]);
}

// ---------------- generic bf16 NT GEMM: C[M,N] (+)= A[M,K] * B[N,K]^T ----------------
// 64x64 tile per block (4 waves, each a 32x32 tile of 2x2 mfma_16x16x32 frags),
// fragments loaded straight from global (everything is L2-resident at this size).
template <bool ACC>
__global__ __launch_bounds__(256) void k_gemm_nt(const __hip_bfloat16* __restrict__ A,
                                                 const __hip_bfloat16* __restrict__ B,
                                                 float* __restrict__ C, int K, int N) {
  const int lane = threadIdx.x & 63;
  const int wid  = threadIdx.x >> 6;
  const int row0 = blockIdx.x * 64 + (wid >> 1) * 32;
  const int col0 = blockIdx.y * 64 + (wid & 1) * 32;
  const int r = lane & 15, g = lane >> 4;
  const bf16x8* pa0 = reinterpret_cast<const bf16x8*>(A + (size_t)(row0 + r) * K) + g;
  const bf16x8* pa1 = reinterpret_cast<const bf16x8*>(A + (size_t)(row0 + 16 + r) * K) + g;
  const bf16x8* pb0 = reinterpret_cast<const bf16x8*>(B + (size_t)(col0 + r) * K) + g;
  const bf16x8* pb1 = reinterpret_cast<const bf16x8*>(B + (size_t)(col0 + 16 + r) * K) + g;
  f32x4 acc00 = {0.f, 0.f, 0.f, 0.f}, acc01 = acc00, acc10 = acc00, acc11 = acc00;
  const int nk = K >> 5;
#pragma unroll 4
  for (int kc = 0; kc < nk; ++kc) {
    bf16x8 a0 = pa0[kc * 4];
    bf16x8 a1 = pa1[kc * 4];
    bf16x8 b0 = pb0[kc * 4];
    bf16x8 b1 = pb1[kc * 4];
    acc00 = __builtin_amdgcn_mfma_f32_16x16x32_bf16(a0, b0, acc00, 0, 0, 0);
    acc01 = __builtin_amdgcn_mfma_f32_16x16x32_bf16(a0, b1, acc01, 0, 0, 0);
    acc10 = __builtin_amdgcn_mfma_f32_16x16x32_bf16(a1, b0, acc10, 0, 0, 0);
    acc11 = __builtin_amdgcn_mfma_f32_16x16x32_bf16(a1, b1, acc11, 0, 0, 0);
  }
  f32x4 accs[2][2] = {{acc00, acc01}, {acc10, acc11}};
#pragma unroll
  for (int fm = 0; fm < 2; ++fm)
#pragma unroll
    for (int fn = 0; fn < 2; ++fn) {
      int orow = row0 + fm * 16 + g * 4;
      int ocol = col0 + fn * 16 + r;
      float* cp = C + (size_t)orow * N + ocol;
#pragma unroll
      for (int j = 0; j < 4; ++j) {
        if (ACC) cp[(size_t)j * N] += accs[fm][fn][j];
        else     cp[(size_t)j * N] = accs[fm][fn][j];
      }
    }
}

// ---------------- causal depthwise conv(4) + bias + silu ----------------
__global__ __launch_bounds__(256) void k_conv_silu(const float* __restrict__ xz,
                                                   const float4* __restrict__ cw,
                                                   const float* __restrict__ cb,
                                                   float* __restrict__ xc,
                                                   __hip_bfloat16* __restrict__ xcb) {
  int idx = blockIdx.x * 256 + threadIdx.x;          // over B*L*DINNER
  int d = idx & (DINNER - 1);
  int l = (idx >> 10) & (SEQL - 1);
  int b = idx >> 18;
  const float* base = xz + ((size_t)b << 19) + d;    // xz[b][.][2048]
  size_t off = (size_t)l << 11;
  float4 w = cw[d];
  float acc = cb[d];
  acc = fmaf(base[off], w.w, acc);
  if (l >= 1) acc = fmaf(base[off - 2048], w.z, acc);
  if (l >= 2) acc = fmaf(base[off - 4096], w.y, acc);
  if (l >= 3) acc = fmaf(base[off - 6144], w.x, acc);
  float sv = acc / (1.f + __expf(-acc));
  xc[idx] = sv;
  xcb[idx] = (__hip_bfloat16)sv;
}

// ---------------- selective scan (+ fused dt-proj/softplus + gating) ----------------
// block = 128 threads: 8 channels (dl) x 16 states (n). grid = B * 128 blocks.
// prologue stages dt (computed from dbl & Wdt), B, C, xc, z into LDS;
// the 256-step sequential loop then runs entirely out of LDS/registers.
__global__ __launch_bounds__(128) void k_scan(const float* __restrict__ dbl,
                                              const float* __restrict__ Wdt,
                                              const float* __restrict__ bdt,
                                              const float* __restrict__ Alog,
                                              const float* __restrict__ Dv,
                                              const float* __restrict__ xc,
                                              const float* __restrict__ xz,
                                              __hip_bfloat16* __restrict__ y) {
  __shared__ float s_dt[SEQL][8];
  __shared__ float s_B[SEQL][16];
  __shared__ float s_C[SEQL][16];
  __shared__ float s_xc[SEQL][8];
  __shared__ float s_z[SEQL][8];
  const int t = threadIdx.x;
  const int n = t & 15, dl = t >> 4;
  const int b = blockIdx.x >> 7;
  const int d0 = (blockIdx.x & 127) << 3;
  const int d = d0 + dl;
  const int bL = b * SEQL;

  for (int idx = t; idx < SEQL * 16; idx += 128) {
    int l = idx >> 4, nn = idx & 15;
    const float* row = dbl + ((size_t)(bL + l) << 6);
    s_B[l][nn] = row[32 + nn];
    s_C[l][nn] = row[48 + nn];
  }
  for (int idx = t; idx < SEQL * 8; idx += 128) {
    int l = idx >> 3, dd = idx & 7;
    s_xc[l][dd] = xc[((size_t)(bL + l) << 10) + d0 + dd];
    s_z[l][dd]  = xz[((size_t)(bL + l) << 11) + DINNER + d0 + dd];
  }
  float wreg[32];
#pragma unroll
  for (int r2 = 0; r2 < 32; ++r2) wreg[r2] = Wdt[(size_t)d * 32 + r2];
  const float bd = bdt[d];
  for (int j = 0; j < 16; ++j) {
    int l = n + (j << 4);
    const float* row = dbl + ((size_t)(bL + l) << 6);
    float acc = bd;
#pragma unroll
    for (int r2 = 0; r2 < 32; ++r2) acc = fmaf(row[r2], wreg[r2], acc);
    s_dt[l][dl] = (acc > 20.f) ? acc : log1pf(__expf(acc));
  }
  __syncthreads();

  const float An = -__expf(Alog[(size_t)d * 16 + n]);
  const float Dd = Dv[d];
  float s = 0.f;
#pragma unroll 2
  for (int l = 0; l < SEQL; ++l) {
    float dtv = s_dt[l][dl];
    float xcv = s_xc[l][dl];
    float dA = __expf(dtv * An);
    s = fmaf(dA, s, dtv * xcv * s_B[l][n]);
    float c = s * s_C[l][n];
    c += __shfl_xor(c, 1);
    c += __shfl_xor(c, 2);
    c += __shfl_xor(c, 4);
    c += __shfl_xor(c, 8);
    if (n == 0) {
      float zv = s_z[l][dl];
      float yv = (c + Dd * xcv) * (zv / (1.f + __expf(-zv)));
      y[((size_t)(bL + l) << 10) + d] = (__hip_bfloat16)yv;
    }
  }
}

// ---------------- launcher ----------------
extern "C" void kernel_launch(void* const* d_in, const int* in_sizes, int n_in,
                              void* d_out, int out_size, void* d_ws, size_t ws_size,
                              hipStream_t stream) {
  (void)in_sizes; (void)n_in; (void)out_size; (void)ws_size;
  const float* x    = (const float*)d_in[0];
  const float* Wi   = (const float*)d_in[1];
  const float* cw   = (const float*)d_in[2];
  const float* cb   = (const float*)d_in[3];
  const float* Wx   = (const float*)d_in[4];
  const float* Wdt  = (const float*)d_in[5];
  const float* bdt  = (const float*)d_in[6];
  const float* Alog = (const float*)d_in[7];
  const float* Dv   = (const float*)d_in[8];
  const float* Wo   = (const float*)d_in[9];
  const float* nw   = (const float*)d_in[10];

  char* ws = (char*)d_ws;
  float*          res = (float*)(ws + 0);                   // 1 MB
  __hip_bfloat16* hn  = (__hip_bfloat16*)(ws + 1048576);    // 0.5 MB
  float*          xz  = (float*)(ws + 1572864);             // 4 MB
  float*          xc  = (float*)(ws + 5767168);             // 2 MB
  __hip_bfloat16* xcb = (__hip_bfloat16*)(ws + 7864320);    // 1 MB
  float*          dbl = (float*)(ws + 8912896);             // 128 KB
  __hip_bfloat16* y   = (__hip_bfloat16*)(ws + 9043968);    // 1 MB
  __hip_bfloat16* wib = (__hip_bfloat16*)(ws + 10092544);   // 14 MB
  __hip_bfloat16* wxb = (__hip_bfloat16*)(ws + 24772608);   // 0.9 MB
  __hip_bfloat16* wob = (__hip_bfloat16*)(ws + 25690112);   // 7 MB

  int nWi = NLAYER * 2048 * 512 / 4;
  int nWx = NLAYER * 64 * 1024 / 4;
  int nWo = NLAYER * 512 * 1024 / 4;
  k_cast_bf16<<<(nWi + 255) / 256, 256, 0, stream>>>(Wi, wib, nWi);
  k_cast_bf16<<<(nWx + 255) / 256, 256, 0, stream>>>(Wx, wxb, nWx);
  k_cast_bf16<<<(nWo + 255) / 256, 256, 0, stream>>>(Wo, wob, nWo);
  k_transpose_in<<<1024, 256, 0, stream>>>(x, res);

  for (int i = 0; i < NLAYER; ++i) {
    k_rmsnorm<<<128, 256, 0, stream>>>(res, nw + i * DIM, hn);
    k_gemm_nt<false><<<dim3(8, 32), 256, 0, stream>>>(hn, wib + (size_t)i * 2048 * 512, xz, 512, 2048);
    k_conv_silu<<<2048, 256, 0, stream>>>(xz, (const float4*)(cw + i * DINNER * 4), cb + i * DINNER, xc, xcb);
    k_gemm_nt<false><<<dim3(8, 1), 256, 0, stream>>>(xcb, wxb + (size_t)i * 64 * 1024, dbl, 1024, 64);
    k_scan<<<256, 128, 0, stream>>>(dbl, Wdt + (size_t)i * DINNER * 32, bdt + i * DINNER,
                                    Alog + (size_t)i * DINNER * 16, Dv + i * DINNER, xc, xz, y);
    k_gemm_nt<true><<<dim3(8, 8), 256, 0, stream>>>(y, wob + (size_t)i * 512 * 1024, res, 1024, 512);
  }
  k_transpose_out<<<1024, 256, 0, stream>>>(res, (float*)d_out);
}

// Round 2
// 605.796 us; speedup vs baseline: 1.5337x; 1.5337x over previous
//
#include <hip/hip_runtime.h>
#include <hip/hip_bf16.h>

typedef __bf16 bf16x8 __attribute__((ext_vector_type(8)));
typedef float  f32x4  __attribute__((ext_vector_type(4)));

#define DIM    512
#define DINNER 1024
#define SEQL   256
#define BATCH  2
#define NLAYER 7   // layer 7's mixer output is discarded by the reference
#define LPAD   260  // row stride for [.][l] LDS arrays: 260%32==4 -> staggered banks

// ---------------- transpose in: res[b][l][d] = x[b][d][l] ----------------
__global__ __launch_bounds__(256) void k_transpose_in(const float* __restrict__ x,
                                                      float* __restrict__ res) {
  int idx = blockIdx.x * 256 + threadIdx.x;          // over B*L*DIM = 262144
  int d = idx & (DIM - 1);
  int l = (idx >> 9) & (SEQL - 1);
  int b = idx >> 17;
  res[idx] = x[((size_t)(b * DIM + d) << 8) + l];
}

// ---------------- transpose out: out[b][c][l] = res[b][l][c] ----------------
__global__ __launch_bounds__(256) void k_transpose_out(const float* __restrict__ res,
                                                       float* __restrict__ out) {
  int idx = blockIdx.x * 256 + threadIdx.x;          // over B*DIM*L
  int l = idx & (SEQL - 1);
  int c = (idx >> 8) & (DIM - 1);
  int b = idx >> 17;
  out[idx] = res[((size_t)(b * SEQL + l) << 9) + c];
}

// ---------------- f32 -> bf16 cast (4 per thread) ----------------
__global__ __launch_bounds__(256) void k_cast_bf16(const float* __restrict__ src,
                                                   __hip_bfloat16* __restrict__ dst, int n4) {
  int i = blockIdx.x * 256 + threadIdx.x;
  if (i >= n4) return;
  float4 v = reinterpret_cast<const float4*>(src)[i];
  struct alignas(8) B4 { __hip_bfloat16 a, b, c, d; };
  B4 o{ (__hip_bfloat16)v.x, (__hip_bfloat16)v.y, (__hip_bfloat16)v.z, (__hip_bfloat16)v.w };
  reinterpret_cast<B4*>(dst)[i] = o;
}

// ---------------- rmsnorm + bf16 cast: one wave per row ----------------
__global__ __launch_bounds__(256) void k_rmsnorm(const float* __restrict__ res,
                                                 const float* __restrict__ w,
                                                 __hip_bfloat16* __restrict__ hn) {
  int wid = threadIdx.x >> 6, lane = threadIdx.x & 63;
  int row = (blockIdx.x << 2) + wid;                 // 512 rows, 4 per block
  const float* r = res + ((size_t)row << 9);
  float v[8];
  float ss = 0.f;
#pragma unroll
  for (int j = 0; j < 8; ++j) { v[j] = r[lane + (j << 6)]; ss = fmaf(v[j], v[j], ss); }
#pragma unroll
  for (int m = 1; m < 64; m <<= 1) ss += __shfl_xor(ss, m);
  float inv = rsqrtf(ss * (1.0f / 512.0f) + 1e-5f);
  __hip_bfloat16* o = hn + ((size_t)row << 9);
#pragma unroll
  for (int j = 0; j < 8; ++j) o[lane + (j << 6)] = (__hip_bfloat16)(v[j] * inv * w[lane + (j << 6)]);
}

// ---------------- generic bf16 NT GEMM: C[M,N] (+)= A[M,K] * B[N,K]^T ----------------
template <bool ACC>
__global__ __launch_bounds__(256) void k_gemm_nt(const __hip_bfloat16* __restrict__ A,
                                                 const __hip_bfloat16* __restrict__ B,
                                                 float* __restrict__ C, int K, int N) {
  const int lane = threadIdx.x & 63;
  const int wid  = threadIdx.x >> 6;
  const int row0 = blockIdx.x * 64 + (wid >> 1) * 32;
  const int col0 = blockIdx.y * 64 + (wid & 1) * 32;
  const int r = lane & 15, g = lane >> 4;
  const bf16x8* pa0 = reinterpret_cast<const bf16x8*>(A + (size_t)(row0 + r) * K) + g;
  const bf16x8* pa1 = reinterpret_cast<const bf16x8*>(A + (size_t)(row0 + 16 + r) * K) + g;
  const bf16x8* pb0 = reinterpret_cast<const bf16x8*>(B + (size_t)(col0 + r) * K) + g;
  const bf16x8* pb1 = reinterpret_cast<const bf16x8*>(B + (size_t)(col0 + 16 + r) * K) + g;
  f32x4 acc00 = {0.f, 0.f, 0.f, 0.f}, acc01 = acc00, acc10 = acc00, acc11 = acc00;
  const int nk = K >> 5;
#pragma unroll 4
  for (int kc = 0; kc < nk; ++kc) {
    bf16x8 a0 = pa0[kc * 4];
    bf16x8 a1 = pa1[kc * 4];
    bf16x8 b0 = pb0[kc * 4];
    bf16x8 b1 = pb1[kc * 4];
    acc00 = __builtin_amdgcn_mfma_f32_16x16x32_bf16(a0, b0, acc00, 0, 0, 0);
    acc01 = __builtin_amdgcn_mfma_f32_16x16x32_bf16(a0, b1, acc01, 0, 0, 0);
    acc10 = __builtin_amdgcn_mfma_f32_16x16x32_bf16(a1, b0, acc10, 0, 0, 0);
    acc11 = __builtin_amdgcn_mfma_f32_16x16x32_bf16(a1, b1, acc11, 0, 0, 0);
  }
  f32x4 accs[2][2] = {{acc00, acc01}, {acc10, acc11}};
#pragma unroll
  for (int fm = 0; fm < 2; ++fm)
#pragma unroll
    for (int fn = 0; fn < 2; ++fn) {
      int orow = row0 + fm * 16 + g * 4;
      int ocol = col0 + fn * 16 + r;
      float* cp = C + (size_t)orow * N + ocol;
#pragma unroll
      for (int j = 0; j < 4; ++j) {
        if (ACC) cp[(size_t)j * N] += accs[fm][fn][j];
        else     cp[(size_t)j * N] = accs[fm][fn][j];
      }
    }
}

// ---------------- causal depthwise conv(4) + bias + silu ----------------
__global__ __launch_bounds__(256) void k_conv_silu(const float* __restrict__ xz,
                                                   const float4* __restrict__ cw,
                                                   const float* __restrict__ cb,
                                                   float* __restrict__ xc,
                                                   __hip_bfloat16* __restrict__ xcb) {
  int idx = blockIdx.x * 256 + threadIdx.x;          // over B*L*DINNER
  int d = idx & (DINNER - 1);
  int l = (idx >> 10) & (SEQL - 1);
  int b = idx >> 18;
  const float* base = xz + ((size_t)b << 19) + d;    // xz[b][.][2048]
  size_t off = (size_t)l << 11;
  float4 w = cw[d];
  float acc = cb[d];
  acc = fmaf(base[off], w.w, acc);
  if (l >= 1) acc = fmaf(base[off - 2048], w.z, acc);
  if (l >= 2) acc = fmaf(base[off - 4096], w.y, acc);
  if (l >= 3) acc = fmaf(base[off - 6144], w.x, acc);
  float sv = acc / (1.f + __expf(-acc));
  xc[idx] = sv;
  xcb[idx] = (__hip_bfloat16)sv;
}

// ---------------- selective scan v2 ----------------
// block = 128 threads: 8 channels (dl) x 16 states (n). grid = B * 128 blocks.
// All staged arrays transposed to [chan][l] (pad LPAD=260) so the sequential
// loop reads via ds_read_b128 (4 steps per read). Per-step cross-lane reduce
// is DEFERRED: c = s*C goes to an LDS chunk buffer; every 64 steps a parallel
// phase reduces over n, applies D*xc + silu(z) gating, stores y coalesced.
// Critical path per step: one FMA. No shuffles, no global ops in the loop.
__global__ __launch_bounds__(128) void k_scan(const float* __restrict__ dbl,
                                              const float* __restrict__ Wdt,
                                              const float* __restrict__ bdt,
                                              const float* __restrict__ Alog,
                                              const float* __restrict__ Dv,
                                              const float* __restrict__ xc,
                                              const float* __restrict__ xz,
                                              __hip_bfloat16* __restrict__ y) {
  __shared__ __align__(16) float s_dt[8][LPAD];
  __shared__ __align__(16) float s_xc[8][LPAD];
  __shared__ __align__(16) float s_B[16][LPAD];
  __shared__ __align__(16) float s_C[16][LPAD];
  __shared__ __align__(16) float s_cp[64][132];
  const int t = threadIdx.x;
  const int n = t & 15, dl = t >> 4;
  const int b = blockIdx.x >> 7;
  const int d0 = (blockIdx.x & 127) << 3;
  const int d = d0 + dl;
  const int bL = b * SEQL;

  // stage B, C transposed: s_B[n][l], s_C[n][l]
  for (int idx = t; idx < SEQL * 16; idx += 128) {
    int l = idx >> 4, nn = idx & 15;
    const float* row = dbl + ((size_t)(bL + l) << 6);
    s_B[nn][l] = row[32 + nn];
    s_C[nn][l] = row[48 + nn];
  }
  // stage xc transposed: s_xc[dd][l]
  for (int idx = t; idx < SEQL * 8; idx += 128) {
    int l = idx >> 3, dd = idx & 7;
    s_xc[dd][l] = xc[((size_t)(bL + l) << 10) + d0 + dd];
  }
  // dt-proj + softplus -> s_dt[dl][l]  (thread (dl,n) does l = n+16j)
  float4 w4[8];
#pragma unroll
  for (int r2 = 0; r2 < 8; ++r2) w4[r2] = reinterpret_cast<const float4*>(Wdt + (size_t)d * 32)[r2];
  const float bd = bdt[d];
  for (int j = 0; j < 16; ++j) {
    int l = n + (j << 4);
    const float4* row = reinterpret_cast<const float4*>(dbl + ((size_t)(bL + l) << 6));
    float acc = bd;
#pragma unroll
    for (int r2 = 0; r2 < 8; ++r2) {
      float4 rv = row[r2];
      acc = fmaf(rv.x, w4[r2].x, acc);
      acc = fmaf(rv.y, w4[r2].y, acc);
      acc = fmaf(rv.z, w4[r2].z, acc);
      acc = fmaf(rv.w, w4[r2].w, acc);
    }
    s_dt[dl][l] = (acc > 20.f) ? acc : log1pf(__expf(acc));
  }
  __syncthreads();

  const float An = -__expf(Alog[(size_t)d * 16 + n]);
  const float Dd = Dv[d];
  float s = 0.f;
  for (int lc = 0; lc < 4; ++lc) {               // 4 chunks of 64 steps
    const int lbase = lc << 6;
#pragma unroll 2
    for (int l4 = 0; l4 < 64; l4 += 4) {
      const int l = lbase + l4;
      float4 dt4 = *reinterpret_cast<const float4*>(&s_dt[dl][l]);
      float4 xc4 = *reinterpret_cast<const float4*>(&s_xc[dl][l]);
      float4 B4  = *reinterpret_cast<const float4*>(&s_B[n][l]);
      float4 C4  = *reinterpret_cast<const float4*>(&s_C[n][l]);
      s = fmaf(__expf(dt4.x * An), s, dt4.x * xc4.x * B4.x);
      s_cp[l4 + 0][t] = s * C4.x;
      s = fmaf(__expf(dt4.y * An), s, dt4.y * xc4.y * B4.y);
      s_cp[l4 + 1][t] = s * C4.y;
      s = fmaf(__expf(dt4.z * An), s, dt4.z * xc4.z * B4.z);
      s_cp[l4 + 2][t] = s * C4.z;
      s = fmaf(__expf(dt4.w * An), s, dt4.w * xc4.w * B4.w);
      s_cp[l4 + 3][t] = s * C4.w;
    }
    __syncthreads();
    // parallel reduce over n + gate + store (512 outputs, 4 per thread)
    for (int idx = t; idx < 64 * 8; idx += 128) {
      int ll = idx >> 3, dd = idx & 7;
      const float* cr = &s_cp[ll][dd << 4];
      float4 a0 = *reinterpret_cast<const float4*>(cr);
      float4 a1 = *reinterpret_cast<const float4*>(cr + 4);
      float4 a2 = *reinterpret_cast<const float4*>(cr + 8);
      float4 a3 = *reinterpret_cast<const float4*>(cr + 12);
      float sum = ((a0.x + a0.y) + (a0.z + a0.w)) + ((a1.x + a1.y) + (a1.z + a1.w))
                + ((a2.x + a2.y) + (a2.z + a2.w)) + ((a3.x + a3.y) + (a3.z + a3.w));
      int l = lbase + ll;
      float xcv = s_xc[dd][l];
      float zv = xz[((size_t)(bL + l) << 11) + DINNER + d0 + dd];
      float yv = (sum + Dv[d0 + dd] * xcv) * (zv / (1.f + __expf(-zv)));
      y[((size_t)(bL + l) << 10) + d0 + dd] = (__hip_bfloat16)yv;
    }
    __syncthreads();
  }
  (void)Dd;
}

// ---------------- launcher ----------------
extern "C" void kernel_launch(void* const* d_in, const int* in_sizes, int n_in,
                              void* d_out, int out_size, void* d_ws, size_t ws_size,
                              hipStream_t stream) {
  (void)in_sizes; (void)n_in; (void)out_size; (void)ws_size;
  const float* x    = (const float*)d_in[0];
  const float* Wi   = (const float*)d_in[1];
  const float* cw   = (const float*)d_in[2];
  const float* cb   = (const float*)d_in[3];
  const float* Wx   = (const float*)d_in[4];
  const float* Wdt  = (const float*)d_in[5];
  const float* bdt  = (const float*)d_in[6];
  const float* Alog = (const float*)d_in[7];
  const float* Dv   = (const float*)d_in[8];
  const float* Wo   = (const float*)d_in[9];
  const float* nw   = (const float*)d_in[10];

  char* ws = (char*)d_ws;
  float*          res = (float*)(ws + 0);                   // 1 MB
  __hip_bfloat16* hn  = (__hip_bfloat16*)(ws + 1048576);    // 0.5 MB
  float*          xz  = (float*)(ws + 1572864);             // 4 MB
  float*          xc  = (float*)(ws + 5767168);             // 2 MB
  __hip_bfloat16* xcb = (__hip_bfloat16*)(ws + 7864320);    // 1 MB
  float*          dbl = (float*)(ws + 8912896);             // 128 KB
  __hip_bfloat16* y   = (__hip_bfloat16*)(ws + 9043968);    // 1 MB
  __hip_bfloat16* wib = (__hip_bfloat16*)(ws + 10092544);   // 14 MB
  __hip_bfloat16* wxb = (__hip_bfloat16*)(ws + 24772608);   // 0.9 MB
  __hip_bfloat16* wob = (__hip_bfloat16*)(ws + 25690112);   // 7 MB

  int nWi = NLAYER * 2048 * 512 / 4;
  int nWx = NLAYER * 64 * 1024 / 4;
  int nWo = NLAYER * 512 * 1024 / 4;
  k_cast_bf16<<<(nWi + 255) / 256, 256, 0, stream>>>(Wi, wib, nWi);
  k_cast_bf16<<<(nWx + 255) / 256, 256, 0, stream>>>(Wx, wxb, nWx);
  k_cast_bf16<<<(nWo + 255) / 256, 256, 0, stream>>>(Wo, wob, nWo);
  k_transpose_in<<<1024, 256, 0, stream>>>(x, res);

  for (int i = 0; i < NLAYER; ++i) {
    k_rmsnorm<<<128, 256, 0, stream>>>(res, nw + i * DIM, hn);
    k_gemm_nt<false><<<dim3(8, 32), 256, 0, stream>>>(hn, wib + (size_t)i * 2048 * 512, xz, 512, 2048);
    k_conv_silu<<<2048, 256, 0, stream>>>(xz, (const float4*)(cw + i * DINNER * 4), cb + i * DINNER, xc, xcb);
    k_gemm_nt<false><<<dim3(8, 1), 256, 0, stream>>>(xcb, wxb + (size_t)i * 64 * 1024, dbl, 1024, 64);
    k_scan<<<256, 128, 0, stream>>>(dbl, Wdt + (size_t)i * DINNER * 32, bdt + i * DINNER,
                                    Alog + (size_t)i * DINNER * 16, Dv + i * DINNER, xc, xz, y);
    k_gemm_nt<true><<<dim3(8, 8), 256, 0, stream>>>(y, wob + (size_t)i * 512 * 1024, res, 1024, 512);
  }
  k_transpose_out<<<1024, 256, 0, stream>>>(res, (float*)d_out);
}

// Round 3
// 506.757 us; speedup vs baseline: 1.8334x; 1.1954x over previous
//
#include <hip/hip_runtime.h>
#include <hip/hip_bf16.h>

typedef __bf16 bf16x8 __attribute__((ext_vector_type(8)));
typedef float  f32x4  __attribute__((ext_vector_type(4)));

#define DIM    512
#define DINNER 1024
#define SEQL   256
#define BATCH  2
#define NLAYER 7   // layer 7's mixer output is discarded by the reference
#define LPAD   260  // row stride for [.][l] LDS arrays: 260%32==4 -> staggered banks
#define NCH    8    // scan chunks
#define CLEN   32   // steps per chunk

// ---------------- transpose in: res[b][l][d] = x[b][d][l] ----------------
__global__ __launch_bounds__(256) void k_transpose_in(const float* __restrict__ x,
                                                      float* __restrict__ res) {
  int idx = blockIdx.x * 256 + threadIdx.x;          // over B*L*DIM = 262144
  int d = idx & (DIM - 1);
  int l = (idx >> 9) & (SEQL - 1);
  int b = idx >> 17;
  res[idx] = x[((size_t)(b * DIM + d) << 8) + l];
}

// ---------------- transpose out: out[b][c][l] = res[b][l][c] ----------------
__global__ __launch_bounds__(256) void k_transpose_out(const float* __restrict__ res,
                                                       float* __restrict__ out) {
  int idx = blockIdx.x * 256 + threadIdx.x;          // over B*DIM*L
  int l = idx & (SEQL - 1);
  int c = (idx >> 8) & (DIM - 1);
  int b = idx >> 17;
  out[idx] = res[((size_t)(b * SEQL + l) << 9) + c];
}

// ---------------- f32 -> bf16 cast of all three weight tensors ----------------
#define N4WI (NLAYER * 2048 * 512 / 4)
#define N4WX (NLAYER * 64 * 1024 / 4)
#define N4WO (NLAYER * 512 * 1024 / 4)
__global__ __launch_bounds__(256) void k_cast_all(const float* __restrict__ Wi,
                                                  const float* __restrict__ Wx,
                                                  const float* __restrict__ Wo,
                                                  __hip_bfloat16* __restrict__ wib,
                                                  __hip_bfloat16* __restrict__ wxb,
                                                  __hip_bfloat16* __restrict__ wob) {
  int i = blockIdx.x * 256 + threadIdx.x;
  const float* src; __hip_bfloat16* dst; int j;
  if (i < N4WI)                { src = Wi; dst = wib; j = i; }
  else if (i < N4WI + N4WX)    { src = Wx; dst = wxb; j = i - N4WI; }
  else if (i < N4WI + N4WX + N4WO) { src = Wo; dst = wob; j = i - N4WI - N4WX; }
  else return;
  float4 v = reinterpret_cast<const float4*>(src)[j];
  struct alignas(8) B4 { __hip_bfloat16 a, b, c, d; };
  B4 o{ (__hip_bfloat16)v.x, (__hip_bfloat16)v.y, (__hip_bfloat16)v.z, (__hip_bfloat16)v.w };
  reinterpret_cast<B4*>(dst)[j] = o;
}

// ---------------- rmsnorm + bf16 cast: one wave per row ----------------
__global__ __launch_bounds__(256) void k_rmsnorm(const float* __restrict__ res,
                                                 const float* __restrict__ w,
                                                 __hip_bfloat16* __restrict__ hn) {
  int wid = threadIdx.x >> 6, lane = threadIdx.x & 63;
  int row = (blockIdx.x << 2) + wid;                 // 512 rows, 4 per block
  const float* r = res + ((size_t)row << 9);
  float v[8];
  float ss = 0.f;
#pragma unroll
  for (int j = 0; j < 8; ++j) { v[j] = r[lane + (j << 6)]; ss = fmaf(v[j], v[j], ss); }
#pragma unroll
  for (int m = 1; m < 64; m <<= 1) ss += __shfl_xor(ss, m);
  float inv = rsqrtf(ss * (1.0f / 512.0f) + 1e-5f);
  __hip_bfloat16* o = hn + ((size_t)row << 9);
#pragma unroll
  for (int j = 0; j < 8; ++j) o[lane + (j << 6)] = (__hip_bfloat16)(v[j] * inv * w[lane + (j << 6)]);
}

// ---------------- generic bf16 NT GEMM: C[M,N] (+)= A[M,K] * B[N,K]^T ----------------
template <bool ACC>
__global__ __launch_bounds__(256) void k_gemm_nt(const __hip_bfloat16* __restrict__ A,
                                                 const __hip_bfloat16* __restrict__ B,
                                                 float* __restrict__ C, int K, int N) {
  const int lane = threadIdx.x & 63;
  const int wid  = threadIdx.x >> 6;
  const int row0 = blockIdx.x * 64 + (wid >> 1) * 32;
  const int col0 = blockIdx.y * 64 + (wid & 1) * 32;
  const int r = lane & 15, g = lane >> 4;
  const bf16x8* pa0 = reinterpret_cast<const bf16x8*>(A + (size_t)(row0 + r) * K) + g;
  const bf16x8* pa1 = reinterpret_cast<const bf16x8*>(A + (size_t)(row0 + 16 + r) * K) + g;
  const bf16x8* pb0 = reinterpret_cast<const bf16x8*>(B + (size_t)(col0 + r) * K) + g;
  const bf16x8* pb1 = reinterpret_cast<const bf16x8*>(B + (size_t)(col0 + 16 + r) * K) + g;
  f32x4 acc00 = {0.f, 0.f, 0.f, 0.f}, acc01 = acc00, acc10 = acc00, acc11 = acc00;
  const int nk = K >> 5;
#pragma unroll 4
  for (int kc = 0; kc < nk; ++kc) {
    bf16x8 a0 = pa0[kc * 4];
    bf16x8 a1 = pa1[kc * 4];
    bf16x8 b0 = pb0[kc * 4];
    bf16x8 b1 = pb1[kc * 4];
    acc00 = __builtin_amdgcn_mfma_f32_16x16x32_bf16(a0, b0, acc00, 0, 0, 0);
    acc01 = __builtin_amdgcn_mfma_f32_16x16x32_bf16(a0, b1, acc01, 0, 0, 0);
    acc10 = __builtin_amdgcn_mfma_f32_16x16x32_bf16(a1, b0, acc10, 0, 0, 0);
    acc11 = __builtin_amdgcn_mfma_f32_16x16x32_bf16(a1, b1, acc11, 0, 0, 0);
  }
  f32x4 accs[2][2] = {{acc00, acc01}, {acc10, acc11}};
#pragma unroll
  for (int fm = 0; fm < 2; ++fm)
#pragma unroll
    for (int fn = 0; fn < 2; ++fn) {
      int orow = row0 + fm * 16 + g * 4;
      int ocol = col0 + fn * 16 + r;
      float* cp = C + (size_t)orow * N + ocol;
#pragma unroll
      for (int j = 0; j < 4; ++j) {
        if (ACC) cp[(size_t)j * N] += accs[fm][fn][j];
        else     cp[(size_t)j * N] = accs[fm][fn][j];
      }
    }
}

// ---------------- causal depthwise conv(4) + bias + silu ----------------
__global__ __launch_bounds__(256) void k_conv_silu(const float* __restrict__ xz,
                                                   const float4* __restrict__ cw,
                                                   const float* __restrict__ cb,
                                                   float* __restrict__ xc,
                                                   __hip_bfloat16* __restrict__ xcb) {
  int idx = blockIdx.x * 256 + threadIdx.x;          // over B*L*DINNER
  int d = idx & (DINNER - 1);
  int l = (idx >> 10) & (SEQL - 1);
  int b = idx >> 18;
  const float* base = xz + ((size_t)b << 19) + d;    // xz[b][.][2048]
  size_t off = (size_t)l << 11;
  float4 w = cw[d];
  float acc = cb[d];
  acc = fmaf(base[off], w.w, acc);
  if (l >= 1) acc = fmaf(base[off - 2048], w.z, acc);
  if (l >= 2) acc = fmaf(base[off - 4096], w.y, acc);
  if (l >= 3) acc = fmaf(base[off - 6144], w.x, acc);
  float sv = acc / (1.f + __expf(-acc));
  xc[idx] = sv;
  xcb[idx] = (__hip_bfloat16)sv;
}

// ---------------- selective scan v3: chunked two-pass, 1024 threads ----------------
// grid = B*128 blocks (8 channels each). block = 1024 thr = 8 chunk-groups x
// (8 dl x 16 n). Chunk-group cg owns steps [32cg, 32cg+32).
//  pass 1: local scan from 0, accumulate P = prod(dA) and s_local (registers).
//  combine: per-lane 7-step prefix over chunk boundaries (exact, linear rec.).
//  pass 2: rerun from true start state, write pair-reduced c-partials to LDS.
//  epilogue: parallel n-reduction + D*xc + silu(z) gate + coalesced store.
__global__ __launch_bounds__(1024) void k_scan(const float* __restrict__ dbl,
                                               const float* __restrict__ Wdt,
                                               const float* __restrict__ bdt,
                                               const float* __restrict__ Alog,
                                               const float* __restrict__ Dv,
                                               const float* __restrict__ xc,
                                               const float* __restrict__ xz,
                                               __hip_bfloat16* __restrict__ y) {
  __shared__ __align__(16) float s_dt[8][LPAD];
  __shared__ __align__(16) float s_xc[8][LPAD];
  __shared__ __align__(16) float s_B[16][LPAD];
  __shared__ __align__(16) float s_C[16][LPAD];
  __shared__ __align__(16) float s_cp[SEQL][68];   // pair-reduced partials
  __shared__ float s_pe[NCH][128];
  __shared__ float s_se[NCH][128];
  const int t = threadIdx.x;
  const int cg = t >> 7;                  // chunk 0..7
  const int tt = t & 127;
  const int n = tt & 15, dl = tt >> 4;
  const int b = blockIdx.x >> 7;
  const int d0 = (blockIdx.x & 127) << 3;
  const int d = d0 + dl;
  const int bL = b * SEQL;

  // ---- stage B, C transposed: s_B[n][l], s_C[n][l] (4 unrolled iters) ----
#pragma unroll
  for (int k = 0; k < 4; ++k) {
    int idx = t + (k << 10);              // 4096
    int l = idx >> 4, nn = idx & 15;
    const float* row = dbl + ((size_t)(bL + l) << 6);
    s_B[nn][l] = row[32 + nn];
    s_C[nn][l] = row[48 + nn];
  }
  // ---- stage xc transposed (2 iters) ----
#pragma unroll
  for (int k = 0; k < 2; ++k) {
    int idx = t + (k << 10);              // 2048
    int l = idx >> 3, dd = idx & 7;
    s_xc[dd][l] = xc[((size_t)(bL + l) << 10) + d0 + dd];
  }
  // ---- dt-proj + softplus: 2 values per thread, same weight row ----
  {
    const int dw = d0 + cg;               // cg doubles as the dl index here
    float4 w4[8];
#pragma unroll
    for (int r2 = 0; r2 < 8; ++r2) w4[r2] = reinterpret_cast<const float4*>(Wdt + (size_t)dw * 32)[r2];
    const float bd = bdt[dw];
#pragma unroll
    for (int k = 0; k < 2; ++k) {
      int l = ((t & 127) << 1) + k;
      const float4* row = reinterpret_cast<const float4*>(dbl + ((size_t)(bL + l) << 6));
      float acc = bd;
#pragma unroll
      for (int r2 = 0; r2 < 8; ++r2) {
        float4 rv = row[r2];
        acc = fmaf(rv.x, w4[r2].x, acc);
        acc = fmaf(rv.y, w4[r2].y, acc);
        acc = fmaf(rv.z, w4[r2].z, acc);
        acc = fmaf(rv.w, w4[r2].w, acc);
      }
      s_dt[cg][l] = (acc > 20.f) ? acc : log1pf(__expf(acc));
    }
  }
  __syncthreads();

  const float An = -__expf(Alog[(size_t)d * 16 + n]);
  const int lb = cg << 5;                 // chunk base step

  // ---- pass 1: local scan, registers only ----
  float s = 0.f, P = 1.f;
#pragma unroll 2
  for (int l4 = 0; l4 < CLEN; l4 += 4) {
    const int l = lb + l4;
    float4 dt4 = *reinterpret_cast<const float4*>(&s_dt[dl][l]);
    float4 xc4 = *reinterpret_cast<const float4*>(&s_xc[dl][l]);
    float4 B4  = *reinterpret_cast<const float4*>(&s_B[n][l]);
    float dA;
    dA = __expf(dt4.x * An); P *= dA; s = fmaf(dA, s, dt4.x * xc4.x * B4.x);
    dA = __expf(dt4.y * An); P *= dA; s = fmaf(dA, s, dt4.y * xc4.y * B4.y);
    dA = __expf(dt4.z * An); P *= dA; s = fmaf(dA, s, dt4.z * xc4.z * B4.z);
    dA = __expf(dt4.w * An); P *= dA; s = fmaf(dA, s, dt4.w * xc4.w * B4.w);
  }
  s_pe[cg][tt] = P;
  s_se[cg][tt] = s;
  __syncthreads();

  // ---- combine: start state for my chunk (wave-uniform loop, <=7 iters) ----
  float ss = 0.f;
  for (int c = 0; c < cg; ++c) ss = fmaf(s_pe[c][tt], ss, s_se[c][tt]);

  // ---- pass 2: true scan from start state; pair-reduced partials to LDS ----
  float s2 = ss;
#pragma unroll 2
  for (int l4 = 0; l4 < CLEN; l4 += 4) {
    const int l = lb + l4;
    float4 dt4 = *reinterpret_cast<const float4*>(&s_dt[dl][l]);
    float4 xc4 = *reinterpret_cast<const float4*>(&s_xc[dl][l]);
    float4 B4  = *reinterpret_cast<const float4*>(&s_B[n][l]);
    float4 C4  = *reinterpret_cast<const float4*>(&s_C[n][l]);
    float dA, c;
    dA = __expf(dt4.x * An); s2 = fmaf(dA, s2, dt4.x * xc4.x * B4.x); c = s2 * C4.x;
    c += __shfl_xor(c, 1); if (!(n & 1)) s_cp[l + 0][(dl << 3) | (n >> 1)] = c;
    dA = __expf(dt4.y * An); s2 = fmaf(dA, s2, dt4.y * xc4.y * B4.y); c = s2 * C4.y;
    c += __shfl_xor(c, 1); if (!(n & 1)) s_cp[l + 1][(dl << 3) | (n >> 1)] = c;
    dA = __expf(dt4.z * An); s2 = fmaf(dA, s2, dt4.z * xc4.z * B4.z); c = s2 * C4.z;
    c += __shfl_xor(c, 1); if (!(n & 1)) s_cp[l + 2][(dl << 3) | (n >> 1)] = c;
    dA = __expf(dt4.w * An); s2 = fmaf(dA, s2, dt4.w * xc4.w * B4.w); c = s2 * C4.w;
    c += __shfl_xor(c, 1); if (!(n & 1)) s_cp[l + 3][(dl << 3) | (n >> 1)] = c;
  }
  __syncthreads();

  // ---- epilogue: n-reduction + gate + store (2 outputs per thread) ----
#pragma unroll
  for (int k = 0; k < 2; ++k) {
    int idx = t + (k << 10);              // 2048 outputs
    int l = idx >> 3, dd = idx & 7;
    const float* cr = &s_cp[l][dd << 3];
    float4 a0 = *reinterpret_cast<const float4*>(cr);
    float4 a1 = *reinterpret_cast<const float4*>(cr + 4);
    float sum = ((a0.x + a0.y) + (a0.z + a0.w)) + ((a1.x + a1.y) + (a1.z + a1.w));
    float xcv = s_xc[dd][l];
    float zv = xz[((size_t)(bL + l) << 11) + DINNER + d0 + dd];
    float yv = (sum + Dv[d0 + dd] * xcv) * (zv / (1.f + __expf(-zv)));
    y[((size_t)(bL + l) << 10) + d0 + dd] = (__hip_bfloat16)yv;
  }
}

// ---------------- launcher ----------------
extern "C" void kernel_launch(void* const* d_in, const int* in_sizes, int n_in,
                              void* d_out, int out_size, void* d_ws, size_t ws_size,
                              hipStream_t stream) {
  (void)in_sizes; (void)n_in; (void)out_size; (void)ws_size;
  const float* x    = (const float*)d_in[0];
  const float* Wi   = (const float*)d_in[1];
  const float* cw   = (const float*)d_in[2];
  const float* cb   = (const float*)d_in[3];
  const float* Wx   = (const float*)d_in[4];
  const float* Wdt  = (const float*)d_in[5];
  const float* bdt  = (const float*)d_in[6];
  const float* Alog = (const float*)d_in[7];
  const float* Dv   = (const float*)d_in[8];
  const float* Wo   = (const float*)d_in[9];
  const float* nw   = (const float*)d_in[10];

  char* ws = (char*)d_ws;
  float*          res = (float*)(ws + 0);                   // 1 MB
  __hip_bfloat16* hn  = (__hip_bfloat16*)(ws + 1048576);    // 0.5 MB
  float*          xz  = (float*)(ws + 1572864);             // 4 MB
  float*          xc  = (float*)(ws + 5767168);             // 2 MB
  __hip_bfloat16* xcb = (__hip_bfloat16*)(ws + 7864320);    // 1 MB
  float*          dbl = (float*)(ws + 8912896);             // 128 KB
  __hip_bfloat16* y   = (__hip_bfloat16*)(ws + 9043968);    // 1 MB
  __hip_bfloat16* wib = (__hip_bfloat16*)(ws + 10092544);   // 14 MB
  __hip_bfloat16* wxb = (__hip_bfloat16*)(ws + 24772608);   // 0.9 MB
  __hip_bfloat16* wob = (__hip_bfloat16*)(ws + 25690112);   // 7 MB

  int n4all = N4WI + N4WX + N4WO;
  k_cast_all<<<(n4all + 255) / 256, 256, 0, stream>>>(Wi, Wx, Wo, wib, wxb, wob);
  k_transpose_in<<<1024, 256, 0, stream>>>(x, res);

  for (int i = 0; i < NLAYER; ++i) {
    k_rmsnorm<<<128, 256, 0, stream>>>(res, nw + i * DIM, hn);
    k_gemm_nt<false><<<dim3(8, 32), 256, 0, stream>>>(hn, wib + (size_t)i * 2048 * 512, xz, 512, 2048);
    k_conv_silu<<<2048, 256, 0, stream>>>(xz, (const float4*)(cw + i * DINNER * 4), cb + i * DINNER, xc, xcb);
    k_gemm_nt<false><<<dim3(8, 1), 256, 0, stream>>>(xcb, wxb + (size_t)i * 64 * 1024, dbl, 1024, 64);
    k_scan<<<256, 1024, 0, stream>>>(dbl, Wdt + (size_t)i * DINNER * 32, bdt + i * DINNER,
                                     Alog + (size_t)i * DINNER * 16, Dv + i * DINNER, xc, xz, y);
    k_gemm_nt<true><<<dim3(8, 8), 256, 0, stream>>>(y, wob + (size_t)i * 512 * 1024, res, 1024, 512);
  }
  k_transpose_out<<<1024, 256, 0, stream>>>(res, (float*)d_out);
}